// Round 4
// baseline (108.687 us; speedup 1.0000x reference)
//
#include <hip/hip_runtime.h>
#include <hip/hip_fp16.h>

#define BATCH 2048

typedef _Float16 f16x8 __attribute__((ext_vector_type(8)));
typedef float f32x4 __attribute__((ext_vector_type(4)));

// xsc geometry (dwords): 2 planes (s=0 even-shift, s=1 odd-shift); shifts
// 2,3 are dword-offset reads.  XROW=17 (16 data + 1 zero pad, odd stride
// spreads row-term banks); XPL%32==8 spreads the plane term.
#define XROW 17       // row stride (dwords)
#define XPL  552      // plane stride: 32*17 + 8
#define XIMG 1104     // image stride = 2 planes
#define PIS  3152     // ps image stride (ushorts): 49*64 + 16 (/2 %32 == 8)

__device__ __forceinline__ float fast_sigmoid(float v) {
    return __builtin_amdgcn_rcpf(1.0f + __builtin_amdgcn_exp2f(v * -1.44269504f));
}

// ---------------------------------------------------------------------------
// Workspace layout (bytes):
//   [0      .. 301056)  W3B  tree B-frags f16 [gi 21][c 14][lane 64][8h]
//   [301056 .. 314496)  FCW2 f32 [g 3][o 10][i 7][f 16]
// ---------------------------------------------------------------------------
#define WS_W3B  0
#define WS_FCW  301056

// k_prep: coalesced float4 read of tree_w + scattered 2B stores.
__global__ __launch_bounds__(256) void k_prep(
    const float* __restrict__ tree_w,
    const float* __restrict__ fc_w,
    ushort* __restrict__ W3B,
    float* __restrict__ FCW2,
    float* __restrict__ out)
{
    int pidx = blockIdx.x * 256 + threadIdx.x;
    if (pidx < 35280) {                     // W3B scatter: 141120 f32 / 4
        float4 v = ((const float4*)tree_w)[pidx];
        int j  = pidx % 7;
        int t1 = pidx / 7;
        int i  = t1 % 7;
        int t2 = t1 / 7;
        int g  = t2 % 3;
        int t3 = t2 / 3;
        int nn = t3 % 15;
        int f  = t3 / 15;
        int gi = g * 7 + i;
        int u  = nn & 7;
        int hi = nn >> 3;
        float vv[4] = {v.x, v.y, v.z, v.w};
        #pragma unroll
        for (int e = 0; e < 4; e++) {
            int ki = e >> 1, kj = e & 1;
            int u27 = ki * 14 + j * 2 + kj;
            int c   = u27 >> 1;
            int qq  = (u27 & 1) * 2 + hi;
            W3B[(size_t)(gi * 14 + c) * 512 + (qq * 16 + f) * 8 + u] =
                __half_as_ushort(__float2half(vv[e]));
        }
    } else if (pidx < 38640) {              // FCW2: 3*10*7*16 f32
        int jj = pidx - 35280;
        int f = jj & 15;
        int r = jj >> 4;
        int i = r % 7;
        int r2 = r / 7;
        int o = r2 % 10;
        int g = r2 / 10;
        FCW2[jj] = fc_w[o * 336 + f * 21 + g * 7 + i];
    } else if (pidx < 48048) {              // zero nn==15 slots (qq odd, u=7)
        int z = pidx - 38640;
        int f  = z & 15;
        int qq = ((z >> 4) & 1) * 2 + 1;
        int r  = z >> 5;
        int c  = r % 14;
        int gi = r / 14;
        W3B[(size_t)(gi * 14 + c) * 512 + (qq * 16 + f) * 8 + 7] = 0;
    } else if (pidx < 68528) {              // zero out[2048][10]
        out[pidx - 48048] = 0.f;
    }
}

// ---------------------------------------------------------------------------
// kF_all: per (image-quad, g).  New in r4:
//  * A2 (conv taps 20..24, row r+4) is only consumed through B2's K-slots
//    0..7, which q==0 lanes supply -> A2 LDS loads exec-masked to q==0
//    (-37% conv LDS read traffic; q!=0 lanes feed zero-init regs x zero B2).
//  * XROW 18->17 (1 pad dword, odd stride).
//  * First tree GEMM's 14 Bf global loads issued before round-2 conv loop
//    (L2 latency hidden under ~1000 cyc of conv work).
// LDS: xsc 8,832 + ps 25,216 = 34,048 B -> 4 blocks/CU.
// ---------------------------------------------------------------------------
__global__ __launch_bounds__(256, 4) void kF_all(
    const float* __restrict__ x,       // [B][3][32][32]
    const float* __restrict__ conv_w,  // [45][25]
    const float* __restrict__ conv_b,  // [45]
    const ushort* __restrict__ W3B,
    const float* __restrict__ FCW2,    // [3][10][7][16] f32
    const float* __restrict__ tree_b,  // [336]
    const float* __restrict__ fc_b,    // [10]
    float* __restrict__ out)           // [2048][10] (zeroed by k_prep)
{
    __shared__ __align__(16) unsigned xsc[2 * XIMG];  // 8,832 B
    __shared__ __align__(16) ushort ps[4 * PIS];      // 25,216 B
    ushort* tsl = (ushort*)xsc;        // [28][16], alias (xsc dead after conv)

    const int tid  = threadIdx.x;
    const int blk  = blockIdx.x;
    const int quad = blk / 3;
    const int g    = blk - quad * 3;
    const int img0 = quad * 4;
    const int lane = tid & 63;
    const int n    = lane & 15;
    const int q    = lane >> 4;
    const int wave = tid >> 6;

    // ---- issue all 4 images' channel-g plane loads early ----
    float4 xv[4];
    #pragma unroll
    for (int im = 0; im < 4; im++)
        xv[im] = ((const float4*)(x + (size_t)(img0 + im) * 3072 + g * 1024))[tid];

    // ---- zero pad dword 16 of every row/plane/image (persists: packs only
    //      touch dwords 0..15) ----
    if (tid < 128) {
        int im = tid >> 6, pl = (tid >> 5) & 1, row = tid & 31;
        xsc[im * XIMG + pl * XPL + row * XROW + 16] = 0u;
    }

    // ---- conv B-frags + folded bias (bs = -bias*log2(e)) ----
    f16x8 B1 = {0, 0, 0, 0, 0, 0, 0, 0};
    f16x8 B2 = {0, 0, 0, 0, 0, 0, 0, 0};
    float bs = 0.f;
    if (n < 15) {
        const float* wrow = conv_w + (g * 15 + n) * 25;
        #pragma unroll
        for (int u = 0; u < 5; u++) B1[u] = (_Float16)wrow[q * 5 + u];
        if (q == 0) {
            #pragma unroll
            for (int u = 0; u < 5; u++) B2[u] = (_Float16)wrow[20 + u];
        }
        bs = conv_b[g * 15 + n] * -1.44269504f;
    }

    // ---- per-lane conv A offsets (dwords), wrap-recurrence, no divides ----
    const int dr = (n >> 1) & 1, dc = n & 1, n4 = n >> 2;
    int aoffd[13];
    {
        int pb = wave * 4 + n4;        // 0..15
        int ph = (pb >= 14) ? 1 : 0;
        int pw = pb - 14 * ph;
        int base = dc * XPL + (dr + q) * XROW;
        #pragma unroll
        for (int it = 0; it < 13; it++) {
            aoffd[it] = base + 2 * ph * XROW + pw;
            pw += 2; ph += 1;
            if (pw >= 14) { pw -= 14; ph += 1; }
        }
    }

    // ---- fused pack: plane0 {d0,d1}, plane1 {t01,t12} ----
    const int prow = tid >> 3, pt = tid & 7;
    auto pack_img = [&](int im2, float4 v) {
        __half2 a = __float22half2_rn(make_float2(v.x, v.y));
        __half2 b = __float22half2_rn(make_float2(v.z, v.w));
        unsigned d0 = *(unsigned*)&a, d1 = *(unsigned*)&b;
        unsigned n0 = (unsigned)__shfl_down((int)d0, 1);
        if (pt == 7) n0 = 0u;                       // col 32 = 0
        unsigned t01 = (d0 >> 16) | (d1 << 16);     // cols +1,+2
        unsigned t12 = (d1 >> 16) | (n0 << 16);     // cols +3,+4
        unsigned* base = xsc + im2 * XIMG + prow * XROW + 2 * pt;
        *(uint2*)(base)       = make_uint2(d0, d1);
        *(uint2*)(base + XPL) = make_uint2(t01, t12);
    };

    // ---- conv tile: both images; A2 loads exec-masked to q==0 lanes
    //      (q!=0 lanes' A2 K-slots multiply zero B2 -> zero-init is safe) ----
    union U { unsigned w[4]; f16x8 v; };
    U A2a, A2b;
    #pragma unroll
    for (int e = 0; e < 4; e++) { A2a.w[e] = 0u; A2b.w[e] = 0u; }

    auto conv_tile2 = [&](int it, ushort* pso) {
        const unsigned* p0 = xsc + aoffd[it];
        const unsigned* p1 = p0 + XIMG;
        U A1a, A1b;
        #pragma unroll
        for (int e = 0; e < 4; e++) {
            A1a.w[e] = p0[e];
            A1b.w[e] = p1[e];
        }
        if (q == 0) {                  // row r+4 = +4*XROW = imm offset 68
            #pragma unroll
            for (int e = 0; e < 4; e++) {
                A2a.w[e] = p0[68 + e];
                A2b.w[e] = p1[68 + e];
            }
        }
        f32x4 da = {0.f, 0.f, 0.f, 0.f}, db = {0.f, 0.f, 0.f, 0.f};
        da = __builtin_amdgcn_mfma_f32_16x16x32_f16(A1a.v, B1, da, 0, 0, 0);
        db = __builtin_amdgcn_mfma_f32_16x16x32_f16(A1b.v, B1, db, 0, 0, 0);
        da = __builtin_amdgcn_mfma_f32_16x16x32_f16(A2a.v, B2, da, 0, 0, 0);
        db = __builtin_amdgcn_mfma_f32_16x16x32_f16(A2b.v, B2, db, 0, 0, 0);
        float mxa = fmaxf(fmaxf(da[0], da[1]), fmaxf(da[2], da[3]));
        float mxb = fmaxf(fmaxf(db[0], db[1]), fmaxf(db[2], db[3]));
        float ea = __builtin_amdgcn_exp2f(fmaf(mxa, -1.44269504f, bs));
        float eb = __builtin_amdgcn_exp2f(fmaf(mxb, -1.44269504f, bs));
        int so = (wave + it * 4) * 64 + lane;   // ps offset = 64*t + lane
        pso[so] =
            __half_as_ushort(__float2half(__builtin_amdgcn_rcpf(1.0f + ea)));
        pso[PIS + so] =
            __half_as_ushort(__float2half(__builtin_amdgcn_rcpf(1.0f + eb)));
    };

    // ---- tree GEMM helper (M=4 images via lane&3) ----
    f16x8 Bf[14];
    auto tree_gemm = [&](int ii) {
        const ushort* ap = ps + (n & 3) * PIS + ii * 448;
        f32x4 D0 = {0.f, 0.f, 0.f, 0.f};
        f32x4 D1 = {0.f, 0.f, 0.f, 0.f};
        #pragma unroll
        for (int c = 0; c < 7; c++) {
            f16x8 Ae = *(const f16x8*)(ap + (2 * c) * 32 + q * 8);
            D0 = __builtin_amdgcn_mfma_f32_16x16x32_f16(Ae, Bf[2 * c], D0, 0, 0, 0);
            f16x8 Ao = *(const f16x8*)(ap + (2 * c + 1) * 32 + q * 8);
            D1 = __builtin_amdgcn_mfma_f32_16x16x32_f16(Ao, Bf[2 * c + 1], D1, 0, 0, 0);
        }
        if (q == 0) {                  // rows 0..3 = images 0..3
            float tb = tree_b[n * 21 + g * 7 + ii];
            #pragma unroll
            for (int im = 0; im < 4; im++) {
                float t = (D0[im] + D1[im]) + tb;
                tsl[(im * 7 + ii) * 16 + n] =
                    __half_as_ushort(__float2half(fast_sigmoid(t)));
            }
        }
    };

    // ---- round 0: pack -> conv -> ps[0..1] ----
    pack_img(0, xv[0]);
    pack_img(1, xv[1]);
    __syncthreads();
    #pragma unroll
    for (int it = 0; it < 12; it++) conv_tile2(it, ps);
    if (wave == 0) conv_tile2(12, ps);
    __syncthreads();

    // ---- round 1: pack -> [Bf prefetch] -> conv -> ps[2..3] ----
    pack_img(0, xv[2]);
    pack_img(1, xv[3]);
    __syncthreads();
    {   // prefetch first tree GEMM's B-frags; latency hides under conv
        const f16x8* Wb = (const f16x8*)W3B + (size_t)(g * 7 + wave) * 896;
        #pragma unroll
        for (int c = 0; c < 14; c++) Bf[c] = Wb[c * 64 + lane];
    }
    #pragma unroll
    for (int it = 0; it < 12; it++) conv_tile2(it, ps + 2 * PIS);
    if (wave == 0) conv_tile2(12, ps + 2 * PIS);
    __syncthreads();

    // ---- tree: 7 per-i GEMMs over waves ----
    tree_gemm(wave);
    if (wave < 3) {
        const f16x8* Wb = (const f16x8*)W3B + (size_t)(g * 7 + wave + 4) * 896;
        #pragma unroll
        for (int c = 0; c < 14; c++) Bf[c] = Wb[c * 64 + lane];
        tree_gemm(wave + 4);
    }
    __syncthreads();

    // ---- partial FC: wave w handles image w, lanes 0..9 = o; atomic add ----
    if (lane < 10) {
        const int im4 = wave, o = lane;
        const uint2* tp = (const uint2*)(tsl + im4 * 112);
        const float4* wp = (const float4*)(FCW2 + (size_t)(g * 10 + o) * 112);
        float acc = (g == 0) ? fc_b[o] : 0.f;
        #pragma unroll
        for (int jj = 0; jj < 28; jj++) {
            float4 w4 = wp[jj];
            uint2 hv = tp[jj];
            float2 p0 = __half22float2(*(const __half2*)&hv.x);
            float2 p1 = __half22float2(*(const __half2*)&hv.y);
            acc = fmaf(p0.x, w4.x, acc);
            acc = fmaf(p0.y, w4.y, acc);
            acc = fmaf(p1.x, w4.z, acc);
            acc = fmaf(p1.y, w4.w, acc);
        }
#if defined(__HIP_PLATFORM_AMD__)
        unsafeAtomicAdd(out + (size_t)(img0 + im4) * 10 + o, acc);
#else
        atomicAdd(out + (size_t)(img0 + im4) * 10 + o, acc);
#endif
    }
}

extern "C" void kernel_launch(void* const* d_in, const int* in_sizes, int n_in,
                              void* d_out, int out_size, void* d_ws, size_t ws_size,
                              hipStream_t stream) {
    const float* x      = (const float*)d_in[0];
    const float* conv_w = (const float*)d_in[1];
    const float* conv_b = (const float*)d_in[2];
    const float* tree_w = (const float*)d_in[3];
    const float* tree_b = (const float*)d_in[4];
    const float* fc_w   = (const float*)d_in[5];
    const float* fc_b   = (const float*)d_in[6];
    float* out = (float*)d_out;

    ushort* W3B  = (ushort*)((char*)d_ws + WS_W3B);
    float*  FCW2 = (float*)((char*)d_ws + WS_FCW);

    k_prep<<<268, 256, 0, stream>>>(tree_w, fc_w, W3B, FCW2, out);
    kF_all<<<512 * 3, 256, 0, stream>>>(x, conv_w, conv_b, W3B, FCW2,
                                        tree_b, fc_b, out);
}